// Round 16
// baseline (122.633 us; speedup 1.0000x reference)
//
#include <hip/hip_runtime.h>
#include <hip/hip_bf16.h>

#define B_ 2
#define S_ 2048
#define HID_ 1024
#define NH_ 16
#define HD_ 64
#define MTOK (B_*S_)
#define LDQKV 3072
#define SCALE_LOG2E 0.18033688011112043f  /* 0.125 * log2(e), folded into Q */

typedef __attribute__((ext_vector_type(8))) __bf16 bf16x8;
typedef __attribute__((ext_vector_type(4))) __bf16 bf16x4;
typedef __attribute__((ext_vector_type(4))) float f32x4;

__device__ __forceinline__ void gl16(__bf16* lds, const __bf16* g) {
  __builtin_amdgcn_global_load_lds(
      (const __attribute__((address_space(1))) void*)g,
      (__attribute__((address_space(3))) void*)lds, 16, 0, 0);
}

// GEMM tile slot-swizzle: row-dependent 16B-slot XOR inside a 64B row.
__device__ __forceinline__ int gswz(int row) { return ((row ^ (row >> 2)) & 3) << 4; }

// ---------------- fused f32 -> bf16 casts (one launch) -------------
__global__ __launch_bounds__(256) void cast_all(
    const float* __restrict__ X,
    const float* __restrict__ Wq, const float* __restrict__ Wk,
    const float* __restrict__ Wv, const float* __restrict__ Wo,
    __bf16* __restrict__ Xb, __bf16* __restrict__ Wqkvb, __bf16* __restrict__ Wob)
{
  int i = blockIdx.x * 256 + threadIdx.x;
  const float* src; __bf16* dst; int j;
  if (i < (1 << 20))              { src = X;  dst = Xb;                 j = i; }
  else if (i < (1<<20)+(1<<18))   { src = Wq; dst = Wqkvb;              j = i - (1<<20); }
  else if (i < (1<<20)+(2<<18))   { src = Wk; dst = Wqkvb + (1<<20);    j = i - (1<<20) - (1<<18); }
  else if (i < (1<<20)+(3<<18))   { src = Wv; dst = Wqkvb + (2<<20);    j = i - (1<<20) - (2<<18); }
  else                            { src = Wo; dst = Wob;                j = i - (1<<20) - (3<<18); }
  float4 v = reinterpret_cast<const float4*>(src)[j];
  bf16x4 o;
  o[0] = (__bf16)v.x; o[1] = (__bf16)v.y; o[2] = (__bf16)v.z; o[3] = (__bf16)v.w;
  reinterpret_cast<bf16x4*>(dst)[j] = o;
}

// ---------------- QKV projection: C = X @ Wqkv^T (+bias, K/V masked)
// 3-buffer LDS, 2-step-ahead prefetch, ONE barrier per K-step.
// Q region is pre-scaled by SCALE_LOG2E (softmax scale folded in).
__global__ __launch_bounds__(256) void gemm_qkv(
    const __bf16* __restrict__ A, const __bf16* __restrict__ W,
    const float* __restrict__ bq, const float* __restrict__ bk,
    const float* __restrict__ bv, const float* __restrict__ mask,
    __bf16* __restrict__ C)
{
  __shared__ __bf16 SM[24576];              // 48 KB: 3x(A 8KB) + 3x(B 8KB)
  const int t = threadIdx.x;
  const int m0 = blockIdx.y * 128;
  const int n0 = blockIdx.x * 128;
  const int lane = t & 63;
  const int w = t >> 6;
  const int wr = (w >> 1) * 64;
  const int wc = (w & 1) * 64;
  const int fr = lane & 15;
  const int kg = lane >> 4;

  f32x4 acc[4][4];
  #pragma unroll
  for (int i = 0; i < 4; i++)
    #pragma unroll
    for (int j = 0; j < 4; j++) acc[i][j] = (f32x4)0.f;

  const int srow = w * 16 + (lane >> 2);
  const int scolb = ((lane & 3) * 16) ^ gswz(srow);
  const __bf16* ap0 = A + (size_t)(m0 + srow) * HID_ + (scolb >> 1);
  const __bf16* ap1 = A + (size_t)(m0 + 64 + srow) * HID_ + (scolb >> 1);
  const __bf16* wp0 = W + (size_t)(n0 + srow) * HID_ + (scolb >> 1);
  const __bf16* wp1 = W + (size_t)(n0 + 64 + srow) * HID_ + (scolb >> 1);

  #define STAGE3(buf, koff) { \
    __bf16* ab = SM + (buf) * 4096; \
    __bf16* bb = SM + 12288 + (buf) * 4096; \
    gl16(ab + w * 512, ap0 + (koff)); \
    gl16(ab + 2048 + w * 512, ap1 + (koff)); \
    gl16(bb + w * 512, wp0 + (koff)); \
    gl16(bb + 2048 + w * 512, wp1 + (koff)); }

  STAGE3(0, 0);
  STAGE3(1, 32);
  int bc = 0, bp2 = 2;
  for (int step = 0; step < 32; ++step) {
    if (step + 1 < 32) { asm volatile("s_waitcnt vmcnt(4)" ::: "memory"); }
    else               { asm volatile("s_waitcnt vmcnt(0)" ::: "memory"); }
    __builtin_amdgcn_sched_barrier(0);
    __builtin_amdgcn_s_barrier();
    if (step + 2 < 32) STAGE3(bp2, (step + 2) * 32);

    const __bf16* ab = SM + bc * 4096;
    const __bf16* bb = SM + 12288 + bc * 4096;
    bf16x8 af[4], bf[4];
    #pragma unroll
    for (int m = 0; m < 4; m++) {
      int row = wr + m*16 + fr;
      af[m] = *(const bf16x8*)((const char*)ab + row * 64 + ((kg * 16) ^ gswz(row)));
    }
    #pragma unroll
    for (int n = 0; n < 4; n++) {
      int row = wc + n*16 + fr;
      bf[n] = *(const bf16x8*)((const char*)bb + row * 64 + ((kg * 16) ^ gswz(row)));
    }
    #pragma unroll
    for (int m = 0; m < 4; m++)
      #pragma unroll
      for (int n = 0; n < 4; n++)
        acc[m][n] = __builtin_amdgcn_mfma_f32_16x16x32_bf16(af[m], bf[n], acc[m][n], 0, 0, 0);

    bc = (bc == 2) ? 0 : bc + 1;
    bp2 = (bp2 == 2) ? 0 : bp2 + 1;
  }

  const int region = n0 >> 10;               // 0=Q 1=K 2=V (block-uniform)
  const float* bias = region == 0 ? bq : (region == 1 ? bk : bv);
  const int nloc = n0 & 1023;

  #pragma unroll
  for (int m = 0; m < 4; m++) {
    #pragma unroll
    for (int r = 0; r < 4; r++) {
      int row = m0 + wr + m*16 + kg*4 + r;
      float rs = region ? mask[row] : SCALE_LOG2E;
      #pragma unroll
      for (int n = 0; n < 4; n++) {
        int c = wc + n*16 + fr;
        C[(size_t)row * LDQKV + n0 + c] = (__bf16)((acc[m][n][r] + bias[nloc + c]) * rs);
      }
    }
  }
}

// ---------------- K^T and V^T in one launch: -> [feat][MTOK] -------
__global__ __launch_bounds__(256) void transpose_kv(
    const __bf16* __restrict__ Kin, const __bf16* __restrict__ Vin,
    __bf16* __restrict__ Kt, __bf16* __restrict__ Vt)
{
  __shared__ __bf16 tile[64][68];
  const int tok0 = blockIdx.x * 64;
  const int f0 = blockIdx.y * 64;
  const __bf16* in = blockIdx.z ? Vin : Kin;
  __bf16* out = blockIdx.z ? Vt : Kt;
  const int t = threadIdx.x;
  const int r = t >> 2;
  const int c0 = (t & 3) * 16;
  const __bf16* src = in + (size_t)(tok0 + r) * LDQKV + f0 + c0;
  *(bf16x8*)&tile[r][c0]     = *(const bf16x8*)src;
  *(bf16x8*)&tile[r][c0 + 8] = *(const bf16x8*)(src + 8);
  __syncthreads();
  bf16x8 o0, o1;
  #pragma unroll
  for (int j = 0; j < 8; j++) { o0[j] = tile[c0 + j][r]; o1[j] = tile[c0 + 8 + j][r]; }
  __bf16* dst = out + (size_t)(f0 + r) * MTOK + tok0 + c0;
  *(bf16x8*)dst = o0;
  *(bf16x8*)(dst + 8) = o1;
}

// ---------------- O projection (64x128 tiles) + state reduce tail ---
// grid (8, 80): y<64 GEMM (m0=y*64, 2 blocks/CU resident); y>=64:
// reduce 8 state partials -> out tail (16 blocks).
__global__ __launch_bounds__(256) void gemm_o(
    const __bf16* __restrict__ A, const __bf16* __restrict__ W,
    const float* __restrict__ bias, const float* __restrict__ part,
    float* __restrict__ C)
{
  if (blockIdx.y >= 64) {
    const int bl = blockIdx.x + (blockIdx.y - 64) * 8;   // 0..15
    const int tid = bl * 256 + threadIdx.x;              // 0..4095
    float* outState = C + (size_t)MTOK * HID_;
    #pragma unroll 4
    for (int e = 0; e < 32; e++) {
      int i = e * 4096 + tid;
      int bh = i >> 12, de = i & 4095;
      float s = 0.f;
      #pragma unroll
      for (int sc = 0; sc < 8; sc++) s += part[(size_t)((bh << 3) + sc) * 4096 + de];
      outState[i] = s;
    }
    return;
  }

  __shared__ __bf16 SM2[18432];   // 36 KB: A 3x(64x32)=6144 | B 3x(128x32)=12288
  const int t = threadIdx.x;
  const int m0 = blockIdx.y * 64;
  const int n0 = blockIdx.x * 128;
  const int lane = t & 63;
  const int w = t >> 6;
  const int wr = (w >> 1) * 32;
  const int wc = (w & 1) * 64;
  const int fr = lane & 15;
  const int kg = lane >> 4;

  f32x4 acc[2][4];
  #pragma unroll
  for (int i = 0; i < 2; i++)
    #pragma unroll
    for (int j = 0; j < 4; j++) acc[i][j] = (f32x4)0.f;

  const int srA = w * 16 + (lane >> 2);            // 0..63
  const int srB0 = w * 32 + (lane >> 2);           // first 16 rows of wave's 32
  const int srB1 = srB0 + 16;
  const __bf16* ap0 = A + (size_t)(m0 + srA) * HID_ + ((((lane & 3) * 16) ^ gswz(srA)) >> 1);
  const __bf16* wp0 = W + (size_t)(n0 + srB0) * HID_ + ((((lane & 3) * 16) ^ gswz(srB0)) >> 1);
  const __bf16* wp1 = W + (size_t)(n0 + srB1) * HID_ + ((((lane & 3) * 16) ^ gswz(srB1)) >> 1);

  #define STAGEO(buf, koff) { \
    gl16(SM2 + (buf) * 2048 + w * 512, ap0 + (koff)); \
    gl16(SM2 + 6144 + (buf) * 4096 + w * 1024, wp0 + (koff)); \
    gl16(SM2 + 6144 + (buf) * 4096 + w * 1024 + 512, wp1 + (koff)); }

  STAGEO(0, 0);
  STAGEO(1, 32);
  int bc = 0, bp2 = 2;
  for (int step = 0; step < 32; ++step) {
    if (step + 1 < 32) { asm volatile("s_waitcnt vmcnt(3)" ::: "memory"); }
    else               { asm volatile("s_waitcnt vmcnt(0)" ::: "memory"); }
    __builtin_amdgcn_sched_barrier(0);
    __builtin_amdgcn_s_barrier();
    if (step + 2 < 32) STAGEO(bp2, (step + 2) * 32);

    const __bf16* ab = SM2 + bc * 2048;
    const __bf16* bb = SM2 + 6144 + bc * 4096;
    bf16x8 af[2], bf[4];
    #pragma unroll
    for (int m = 0; m < 2; m++) {
      int row = wr + m*16 + fr;
      af[m] = *(const bf16x8*)((const char*)ab + row * 64 + ((kg * 16) ^ gswz(row)));
    }
    #pragma unroll
    for (int n = 0; n < 4; n++) {
      int row = wc + n*16 + fr;
      bf[n] = *(const bf16x8*)((const char*)bb + row * 64 + ((kg * 16) ^ gswz(row)));
    }
    #pragma unroll
    for (int m = 0; m < 2; m++)
      #pragma unroll
      for (int n = 0; n < 4; n++)
        acc[m][n] = __builtin_amdgcn_mfma_f32_16x16x32_bf16(af[m], bf[n], acc[m][n], 0, 0, 0);

    bc = (bc == 2) ? 0 : bc + 1;
    bp2 = (bp2 == 2) ? 0 : bp2 + 1;
  }

  #pragma unroll
  for (int m = 0; m < 2; m++) {
    #pragma unroll
    for (int r = 0; r < 4; r++) {
      int row = m0 + wr + m*16 + kg*4 + r;
      #pragma unroll
      for (int n = 0; n < 4; n++) {
        int col = n0 + wc + n*16 + fr;
        C[(size_t)row * HID_ + col] = acc[m][n][r] + bias[col];
      }
    }
  }
}

// ---------------- flash attention + fused state tail ---------------
__device__ __forceinline__ bf16x8 ld_swz(const __bf16* base, int row, int xb) {
  return *(const bf16x8*)((const char*)base + row * 128 + (xb ^ ((row & 7) << 4)));
}
__device__ __forceinline__ void st_swz16(__bf16* base, int row, int colbyte, __bf16 v) {
  *(__bf16*)((char*)base + row * 128 + (colbyte ^ ((row & 7) << 4))) = v;
}
__device__ __forceinline__ bf16x8 ld_swz256(const __bf16* base, int row, int xb) {
  return *(const bf16x8*)((const char*)base + row * 256 + (xb ^ ((row & 7) << 4)));
}

__device__ __forceinline__ void attn_tile(
    const __bf16* __restrict__ ks, const __bf16* __restrict__ vs,
    const bool (&okm)[4], __bf16* __restrict__ pw,
    const bf16x8 (&qa)[2], f32x4 (&acc)[4], f32x4& accl,
    const bf16x8 ones, int q0w, int kt, int fc, int kg)
{
  // ---- QK^T (Q pre-scaled by 0.125*log2e) ----
  f32x4 s[4];
  #pragma unroll
  for (int n = 0; n < 4; n++) s[n] = (f32x4)0.f;
  __builtin_amdgcn_s_setprio(1);
  #pragma unroll
  for (int kd = 0; kd < 2; kd++)
    #pragma unroll
    for (int n = 0; n < 4; n++) {
      bf16x8 kf = ld_swz(ks, n * 16 + fc, kd * 64 + kg * 16);
      s[n] = __builtin_amdgcn_mfma_f32_16x16x32_bf16(qa[kd], kf, s[n], 0, 0, 0);
    }
  __builtin_amdgcn_s_setprio(0);

  const int g4 = kg * 4;
  const bool fullt = (kt * 64 + 63 <= q0w);   // wave-uniform: no causal edge
  if (fullt) {
    #pragma unroll
    for (int r = 0; r < 4; r++)
      #pragma unroll
      for (int n = 0; n < 4; n++) {
        float p = okm[n] ? __builtin_amdgcn_exp2f(s[n][r]) : 0.f;
        st_swz16(pw, g4 + r, (n * 16 + fc) * 2, (__bf16)p);
      }
  } else {
    #pragma unroll
    for (int r = 0; r < 4; r++) {
      const int qg = q0w + g4 + r;
      #pragma unroll
      for (int n = 0; n < 4; n++) {
        bool ok = okm[n] && (kt * 64 + n * 16 + fc <= qg);
        float p = ok ? __builtin_amdgcn_exp2f(s[n][r]) : 0.f;
        st_swz16(pw, g4 + r, (n * 16 + fc) * 2, (__bf16)p);
      }
    }
  }

  // ---- PV (+ row-sum l via ones-MFMA) ----
  __builtin_amdgcn_s_setprio(1);
  #pragma unroll
  for (int kc = 0; kc < 2; kc++) {
    bf16x8 pf = ld_swz(pw, fc, kc * 64 + kg * 16);
    accl = __builtin_amdgcn_mfma_f32_16x16x32_bf16(pf, ones, accl, 0, 0, 0);
    #pragma unroll
    for (int n = 0; n < 4; n++) {
      bf16x8 vf = ld_swz(vs, n * 16 + fc, kc * 64 + kg * 16);
      acc[n] = __builtin_amdgcn_mfma_f32_16x16x32_bf16(pf, vf, acc[n], 0, 0, 0);
    }
  }
  __builtin_amdgcn_s_setprio(0);
}

// grid (32, 40): y<32 flash, y>=32 state. LDS = 32 KB exactly ->
// 5 blocks/CU. K double-buffered; V single-buffered, staged after the
// post-compute barrier. qt permutation balances per-CU load.
__global__ __launch_bounds__(256) void flash_state(
    const __bf16* __restrict__ Q, const __bf16* __restrict__ K,
    const __bf16* __restrict__ Vt, const float* __restrict__ mask,
    __bf16* __restrict__ O, const __bf16* __restrict__ Kt,
    float* __restrict__ part)
{
  __shared__ __bf16 SMEM[16384];   // 32 KB: K dbuf 16K | V 8K | Ps 8K

  const int t = threadIdx.x;
  const int w = t >> 6;
  const int lane = t & 63;
  const int fc = lane & 15;
  const int kg = lane >> 4;

  if (blockIdx.y >= 32) {
    // -------- state = K^T V (per head, 256-token slab, 2 chunks) --------
    const int bh = blockIdx.x, sc = blockIdx.y - 32;
    const int b = bh >> 4, h = bh & 15;
    __bf16* Kl = &SMEM[0];
    __bf16* Vl = &SMEM[8192];
    const int rloc = lane >> 4;
    const int cb = (lane & 15) * 16;

    f32x4 acc[4];
    #pragma unroll
    for (int n = 0; n < 4; n++) acc[n] = (f32x4)0.f;

    for (int ch = 0; ch < 2; ch++) {
      const size_t colbase = (size_t)b * S_ + sc * 256 + ch * 128;
      __syncthreads();
      #pragma unroll
      for (int c = 0; c < 4; c++) {
        int row = w * 16 + c * 4 + rloc;
        int scol = (cb ^ ((row & 7) << 4)) >> 1;
        gl16(&Kl[(w * 16 + c * 4) * 128], Kt + (size_t)(h * HD_ + row) * MTOK + colbase + scol);
        gl16(&Vl[(w * 16 + c * 4) * 128], Vt + (size_t)(h * HD_ + row) * MTOK + colbase + scol);
      }
      __syncthreads();

      #pragma unroll
      for (int ks = 0; ks < 4; ks++) {
        bf16x8 af = ld_swz256(Kl, w * 16 + fc, ks * 64 + kg * 16);
        #pragma unroll
        for (int n = 0; n < 4; n++) {
          bf16x8 bfr = ld_swz256(Vl, n * 16 + fc, ks * 64 + kg * 16);
          acc[n] = __builtin_amdgcn_mfma_f32_16x16x32_bf16(af, bfr, acc[n], 0, 0, 0);
        }
      }
    }

    float* dst = part + ((size_t)((bh << 3) + sc) << 12);
    #pragma unroll
    for (int n = 0; n < 4; n++)
      #pragma unroll
      for (int r = 0; r < 4; r++)
        dst[(w * 16 + kg * 4 + r) * 64 + n * 16 + fc] = acc[n][r];
    return;
  }

  // ------------------------- flash attention -------------------------
  const int bh = blockIdx.x;
  const int ya = (int)blockIdx.y & 7;
  const int yg = (int)blockIdx.y >> 3;
  const int qt = (yg == 0) ? 31 - ya : (yg == 1) ? 16 + ya
               : (yg == 2) ? 15 - ya : ya;   // per-CU quadruple sums to 62
  const int b = bh >> 4, h = bh & 15;
  const int g4 = kg * 4;

  const int q0w = qt * 64 + w * 16;
  const size_t tokbase = (size_t)b * S_;

  const int rr = lane >> 3;
  const int cswz = ((lane & 7) ^ rr) * 8;
  const int ktmax = qt;

  __bf16* Vsb = &SMEM[8192];
  __bf16* pw = &SMEM[12288 + w * 1024];

  bf16x8 qa[2];
  {
    const __bf16* qp = Q + (tokbase + q0w + fc) * LDQKV + h * HD_;
    qa[0] = *(const bf16x8*)(qp + kg * 8);
    qa[1] = *(const bf16x8*)(qp + 32 + kg * 8);
  }

  const __bf16* kp0 = K + (tokbase + (size_t)(w * 16 + rr)) * LDQKV + h * HD_ + cswz;
  const __bf16* kp1 = kp0 + (size_t)8 * LDQKV;
  const __bf16* vp0 = Vt + (size_t)(h * HD_ + w * 16 + rr) * MTOK + tokbase + cswz;
  const __bf16* vp1 = vp0 + (size_t)8 * MTOK;

  gl16(&SMEM[(w * 16) * 64],     kp0);
  gl16(&SMEM[(w * 16 + 8) * 64], kp1);
  kp0 += (size_t)64 * LDQKV; kp1 += (size_t)64 * LDQKV;
  gl16(&Vsb[(w * 16) * 64],     vp0);
  gl16(&Vsb[(w * 16 + 8) * 64], vp1);
  vp0 += 64; vp1 += 64;

  const float* mp = mask + tokbase + fc;
  float mnxt[4];
  #pragma unroll
  for (int n = 0; n < 4; n++) mnxt[n] = mp[n * 16];

  bf16x8 ones;
  #pragma unroll
  for (int j = 0; j < 8; j++) ones[j] = (__bf16)1.f;

  f32x4 acc[4], accl;
  #pragma unroll
  for (int n = 0; n < 4; n++) acc[n] = (f32x4)0.f;
  accl = (f32x4)0.f;

  for (int kt = 0; kt <= ktmax; ++kt) {
    float mcur[4];
    #pragma unroll
    for (int n = 0; n < 4; n++) mcur[n] = mnxt[n];

    if (kt < ktmax) {
      #pragma unroll
      for (int n = 0; n < 4; n++) mnxt[n] = mp[(kt + 1) * 64 + n * 16];
      __bf16* kb = &SMEM[((kt + 1) & 1) * 4096];
      gl16(&kb[(w * 16) * 64],     kp0);
      gl16(&kb[(w * 16 + 8) * 64], kp1);
      kp0 += (size_t)64 * LDQKV; kp1 += (size_t)64 * LDQKV;
      asm volatile("s_waitcnt vmcnt(6)" ::: "memory");
    } else {
      asm volatile("s_waitcnt vmcnt(0)" ::: "memory");
    }
    __builtin_amdgcn_sched_barrier(0);
    __builtin_amdgcn_s_barrier();

    bool okm[4];
    #pragma unroll
    for (int n = 0; n < 4; n++) okm[n] = (mcur[n] != 0.f);

    attn_tile(&SMEM[(kt & 1) * 4096], Vsb, okm, pw, qa, acc, accl, ones, q0w, kt, fc, kg);

    __builtin_amdgcn_s_barrier();

    if (kt < ktmax) {
      gl16(&Vsb[(w * 16) * 64],     vp0);
      gl16(&Vsb[(w * 16 + 8) * 64], vp1);
      vp0 += 64; vp1 += 64;
    }
  }

  #pragma unroll
  for (int r = 0; r < 4; r++) {
    float inv = accl[r] > 0.f ? 1.f / accl[r] : 0.f;
    __bf16* op = O + (tokbase + q0w + g4 + r) * HID_ + h * HD_;
    #pragma unroll
    for (int n = 0; n < 4; n++)
      op[n * 16 + fc] = (__bf16)(acc[n][r] * inv);
  }
}

// -------------------------------------------------------------------
extern "C" void kernel_launch(void* const* d_in, const int* in_sizes, int n_in,
                              void* d_out, int out_size, void* d_ws, size_t ws_size,
                              hipStream_t stream)
{
  const float* hs   = (const float*)d_in[0];
  const float* mask = (const float*)d_in[1];
  const float* Wq   = (const float*)d_in[2];
  const float* bq   = (const float*)d_in[3];
  const float* Wk   = (const float*)d_in[4];
  const float* bk   = (const float*)d_in[5];
  const float* Wv   = (const float*)d_in[6];
  const float* bv   = (const float*)d_in[7];
  const float* Wo   = (const float*)d_in[8];
  const float* bo   = (const float*)d_in[9];
  float* out = (float*)d_out;

  char* ws = (char*)d_ws;
  __bf16* Wqkvb = (__bf16*)(ws);                 // 6 MB; dead after gemm_qkv -> part
  __bf16* Wob   = (__bf16*)(ws + (6u  << 20));   // 2 MB; live until gemm_o
  __bf16* Xb    = (__bf16*)(ws + (8u  << 20));   // 8 MB; dead after qkv -> Vt
  __bf16* QKV   = (__bf16*)(ws + (16u << 20));   // 24 MB [4096][3072]
  __bf16* Ob    = (__bf16*)(ws + (40u << 20));   // 8 MB flash output
  __bf16* Ktg   = (__bf16*)(ws + (48u << 20));   // 8 MB [HID][MTOK]

  cast_all<<<8192, 256, 0, stream>>>(hs, Wq, Wk, Wv, Wo, Xb, Wqkvb, Wob);

  gemm_qkv<<<dim3(LDQKV / 128, MTOK / 128), 256, 0, stream>>>(
      Xb, Wqkvb, bq, bk, bv, mask, QKV);

  // Xb dead -> V^T
  __bf16* Vtg = Xb;
  transpose_kv<<<dim3(MTOK / 64, HID_ / 64, 2), 256, 0, stream>>>(
      QKV + 1024, QKV + 2048, Ktg, Vtg);

  // Wqkvb dead -> state partials (32*8*4096 f32 = 4 MB)
  float* part = (float*)Wqkvb;

  flash_state<<<dim3(B_ * NH_, 40), 256, 0, stream>>>(
      QKV, QKV + 1024, Vtg, mask, Ob, Ktg, part);

  gemm_o<<<dim3(HID_ / 128, 80), 256, 0, stream>>>(Ob, Wob, bo, part, out);
}

// Round 17
// 119.408 us; speedup vs baseline: 1.0270x; 1.0270x over previous
//
#include <hip/hip_runtime.h>
#include <hip/hip_bf16.h>

#define B_ 2
#define S_ 2048
#define HID_ 1024
#define NH_ 16
#define HD_ 64
#define MTOK (B_*S_)
#define LDQKV 3072
#define SCALE_LOG2E 0.18033688011112043f  /* 0.125 * log2(e), folded into Q */

typedef __attribute__((ext_vector_type(8))) __bf16 bf16x8;
typedef __attribute__((ext_vector_type(4))) __bf16 bf16x4;
typedef __attribute__((ext_vector_type(4))) float f32x4;

__device__ __forceinline__ void gl16(__bf16* lds, const __bf16* g) {
  __builtin_amdgcn_global_load_lds(
      (const __attribute__((address_space(1))) void*)g,
      (__attribute__((address_space(3))) void*)lds, 16, 0, 0);
}

// GEMM tile slot-swizzle: row-dependent 16B-slot XOR inside a 64B row.
__device__ __forceinline__ int gswz(int row) { return ((row ^ (row >> 2)) & 3) << 4; }

// ---------------- fused f32 -> bf16 casts (one launch) -------------
// 2048 blocks, grid-stride 4 float4 per thread (G11).
__global__ __launch_bounds__(256) void cast_all(
    const float* __restrict__ X,
    const float* __restrict__ Wq, const float* __restrict__ Wk,
    const float* __restrict__ Wv, const float* __restrict__ Wo,
    __bf16* __restrict__ Xb, __bf16* __restrict__ Wqkvb, __bf16* __restrict__ Wob)
{
  const int base = blockIdx.x * 256 + threadIdx.x;   // 0..524287
  #pragma unroll
  for (int k = 0; k < 4; k++) {
    int i = base + k * 524288;                       // covers 2M float4 exactly
    const float* src; __bf16* dst; int j;
    if (i < (1 << 20))              { src = X;  dst = Xb;                 j = i; }
    else if (i < (1<<20)+(1<<18))   { src = Wq; dst = Wqkvb;              j = i - (1<<20); }
    else if (i < (1<<20)+(2<<18))   { src = Wk; dst = Wqkvb + (1<<20);    j = i - (1<<20) - (1<<18); }
    else if (i < (1<<20)+(3<<18))   { src = Wv; dst = Wqkvb + (2<<20);    j = i - (1<<20) - (2<<18); }
    else                            { src = Wo; dst = Wob;                j = i - (1<<20) - (3<<18); }
    float4 v = reinterpret_cast<const float4*>(src)[j];
    bf16x4 o;
    o[0] = (__bf16)v.x; o[1] = (__bf16)v.y; o[2] = (__bf16)v.z; o[3] = (__bf16)v.w;
    reinterpret_cast<bf16x4*>(dst)[j] = o;
  }
}

// ---------------- QKV projection: C = X @ Wqkv^T (+bias, K/V masked)
// 3-buffer LDS, 2-step-ahead prefetch, ONE barrier per K-step.
// Q region is pre-scaled by SCALE_LOG2E (softmax scale folded in).
__global__ __launch_bounds__(256) void gemm_qkv(
    const __bf16* __restrict__ A, const __bf16* __restrict__ W,
    const float* __restrict__ bq, const float* __restrict__ bk,
    const float* __restrict__ bv, const float* __restrict__ mask,
    __bf16* __restrict__ C)
{
  __shared__ __bf16 SM[24576];              // 48 KB: 3x(A 8KB) + 3x(B 8KB)
  const int t = threadIdx.x;
  const int m0 = blockIdx.y * 128;
  const int n0 = blockIdx.x * 128;
  const int lane = t & 63;
  const int w = t >> 6;
  const int wr = (w >> 1) * 64;
  const int wc = (w & 1) * 64;
  const int fr = lane & 15;
  const int kg = lane >> 4;

  f32x4 acc[4][4];
  #pragma unroll
  for (int i = 0; i < 4; i++)
    #pragma unroll
    for (int j = 0; j < 4; j++) acc[i][j] = (f32x4)0.f;

  const int srow = w * 16 + (lane >> 2);
  const int scolb = ((lane & 3) * 16) ^ gswz(srow);
  const __bf16* ap0 = A + (size_t)(m0 + srow) * HID_ + (scolb >> 1);
  const __bf16* ap1 = A + (size_t)(m0 + 64 + srow) * HID_ + (scolb >> 1);
  const __bf16* wp0 = W + (size_t)(n0 + srow) * HID_ + (scolb >> 1);
  const __bf16* wp1 = W + (size_t)(n0 + 64 + srow) * HID_ + (scolb >> 1);

  #define STAGE3(buf, koff) { \
    __bf16* ab = SM + (buf) * 4096; \
    __bf16* bb = SM + 12288 + (buf) * 4096; \
    gl16(ab + w * 512, ap0 + (koff)); \
    gl16(ab + 2048 + w * 512, ap1 + (koff)); \
    gl16(bb + w * 512, wp0 + (koff)); \
    gl16(bb + 2048 + w * 512, wp1 + (koff)); }

  STAGE3(0, 0);
  STAGE3(1, 32);
  int bc = 0, bp2 = 2;
  for (int step = 0; step < 32; ++step) {
    if (step + 1 < 32) { asm volatile("s_waitcnt vmcnt(4)" ::: "memory"); }
    else               { asm volatile("s_waitcnt vmcnt(0)" ::: "memory"); }
    __builtin_amdgcn_sched_barrier(0);
    __builtin_amdgcn_s_barrier();
    if (step + 2 < 32) STAGE3(bp2, (step + 2) * 32);

    const __bf16* ab = SM + bc * 4096;
    const __bf16* bb = SM + 12288 + bc * 4096;
    bf16x8 af[4], bf[4];
    #pragma unroll
    for (int m = 0; m < 4; m++) {
      int row = wr + m*16 + fr;
      af[m] = *(const bf16x8*)((const char*)ab + row * 64 + ((kg * 16) ^ gswz(row)));
    }
    #pragma unroll
    for (int n = 0; n < 4; n++) {
      int row = wc + n*16 + fr;
      bf[n] = *(const bf16x8*)((const char*)bb + row * 64 + ((kg * 16) ^ gswz(row)));
    }
    #pragma unroll
    for (int m = 0; m < 4; m++)
      #pragma unroll
      for (int n = 0; n < 4; n++)
        acc[m][n] = __builtin_amdgcn_mfma_f32_16x16x32_bf16(af[m], bf[n], acc[m][n], 0, 0, 0);

    bc = (bc == 2) ? 0 : bc + 1;
    bp2 = (bp2 == 2) ? 0 : bp2 + 1;
  }

  const int region = n0 >> 10;               // 0=Q 1=K 2=V (block-uniform)
  const float* bias = region == 0 ? bq : (region == 1 ? bk : bv);
  const int nloc = n0 & 1023;

  #pragma unroll
  for (int m = 0; m < 4; m++) {
    #pragma unroll
    for (int r = 0; r < 4; r++) {
      int row = m0 + wr + m*16 + kg*4 + r;
      float rs = region ? mask[row] : SCALE_LOG2E;
      #pragma unroll
      for (int n = 0; n < 4; n++) {
        int c = wc + n*16 + fr;
        C[(size_t)row * LDQKV + n0 + c] = (__bf16)((acc[m][n][r] + bias[nloc + c]) * rs);
      }
    }
  }
}

// ---------------- K^T and V^T in one launch: -> [feat][MTOK] -------
__global__ __launch_bounds__(256) void transpose_kv(
    const __bf16* __restrict__ Kin, const __bf16* __restrict__ Vin,
    __bf16* __restrict__ Kt, __bf16* __restrict__ Vt)
{
  __shared__ __bf16 tile[64][68];
  const int tok0 = blockIdx.x * 64;
  const int f0 = blockIdx.y * 64;
  const __bf16* in = blockIdx.z ? Vin : Kin;
  __bf16* out = blockIdx.z ? Vt : Kt;
  const int t = threadIdx.x;
  const int r = t >> 2;
  const int c0 = (t & 3) * 16;
  const __bf16* src = in + (size_t)(tok0 + r) * LDQKV + f0 + c0;
  *(bf16x8*)&tile[r][c0]     = *(const bf16x8*)src;
  *(bf16x8*)&tile[r][c0 + 8] = *(const bf16x8*)(src + 8);
  __syncthreads();
  bf16x8 o0, o1;
  #pragma unroll
  for (int j = 0; j < 8; j++) { o0[j] = tile[c0 + j][r]; o1[j] = tile[c0 + 8 + j][r]; }
  __bf16* dst = out + (size_t)(f0 + r) * MTOK + tok0 + c0;
  *(bf16x8*)dst = o0;
  *(bf16x8*)(dst + 8) = o1;
}

// ---------------- O projection + state reduction tail --------------
// grid (8, 34): y<32 GEMM 128x128; y>=32 reduce 8 state partials.
__global__ __launch_bounds__(256) void gemm_o(
    const __bf16* __restrict__ A, const __bf16* __restrict__ W,
    const float* __restrict__ bias, const float* __restrict__ part,
    float* __restrict__ C)
{
  if (blockIdx.y >= 32) {
    const int bl = blockIdx.x + (blockIdx.y - 32) * 8;   // 0..15
    const int tid = bl * 256 + threadIdx.x;              // 0..4095
    float* outState = C + (size_t)MTOK * HID_;
    #pragma unroll 4
    for (int e = 0; e < 32; e++) {
      int i = e * 4096 + tid;
      int bh = i >> 12, de = i & 4095;
      float s = 0.f;
      #pragma unroll
      for (int sc = 0; sc < 8; sc++) s += part[(size_t)((bh << 3) + sc) * 4096 + de];
      outState[i] = s;
    }
    return;
  }

  __shared__ __bf16 SM[24576];
  const int t = threadIdx.x;
  const int m0 = blockIdx.y * 128;
  const int n0 = blockIdx.x * 128;
  const int lane = t & 63;
  const int w = t >> 6;
  const int wr = (w >> 1) * 64;
  const int wc = (w & 1) * 64;
  const int fr = lane & 15;
  const int kg = lane >> 4;

  f32x4 acc[4][4];
  #pragma unroll
  for (int i = 0; i < 4; i++)
    #pragma unroll
    for (int j = 0; j < 4; j++) acc[i][j] = (f32x4)0.f;

  const int srow = w * 16 + (lane >> 2);
  const int scolb = ((lane & 3) * 16) ^ gswz(srow);
  const __bf16* ap0 = A + (size_t)(m0 + srow) * HID_ + (scolb >> 1);
  const __bf16* ap1 = A + (size_t)(m0 + 64 + srow) * HID_ + (scolb >> 1);
  const __bf16* wp0 = W + (size_t)(n0 + srow) * HID_ + (scolb >> 1);
  const __bf16* wp1 = W + (size_t)(n0 + 64 + srow) * HID_ + (scolb >> 1);

  STAGE3(0, 0);
  STAGE3(1, 32);
  int bc = 0, bp2 = 2;
  for (int step = 0; step < 32; ++step) {
    if (step + 1 < 32) { asm volatile("s_waitcnt vmcnt(4)" ::: "memory"); }
    else               { asm volatile("s_waitcnt vmcnt(0)" ::: "memory"); }
    __builtin_amdgcn_sched_barrier(0);
    __builtin_amdgcn_s_barrier();
    if (step + 2 < 32) STAGE3(bp2, (step + 2) * 32);

    const __bf16* ab = SM + bc * 4096;
    const __bf16* bb = SM + 12288 + bc * 4096;
    bf16x8 af[4], bf[4];
    #pragma unroll
    for (int m = 0; m < 4; m++) {
      int row = wr + m*16 + fr;
      af[m] = *(const bf16x8*)((const char*)ab + row * 64 + ((kg * 16) ^ gswz(row)));
    }
    #pragma unroll
    for (int n = 0; n < 4; n++) {
      int row = wc + n*16 + fr;
      bf[n] = *(const bf16x8*)((const char*)bb + row * 64 + ((kg * 16) ^ gswz(row)));
    }
    #pragma unroll
    for (int m = 0; m < 4; m++)
      #pragma unroll
      for (int n = 0; n < 4; n++)
        acc[m][n] = __builtin_amdgcn_mfma_f32_16x16x32_bf16(af[m], bf[n], acc[m][n], 0, 0, 0);

    bc = (bc == 2) ? 0 : bc + 1;
    bp2 = (bp2 == 2) ? 0 : bp2 + 1;
  }

  #pragma unroll
  for (int m = 0; m < 4; m++) {
    #pragma unroll
    for (int r = 0; r < 4; r++) {
      int row = m0 + wr + m*16 + kg*4 + r;
      #pragma unroll
      for (int n = 0; n < 4; n++) {
        int col = n0 + wc + n*16 + fr;
        C[(size_t)row * HID_ + col] = acc[m][n][r] + bias[col];
      }
    }
  }
}

// ---------------- flash attention + fused state tail ---------------
__device__ __forceinline__ bf16x8 ld_swz(const __bf16* base, int row, int xb) {
  return *(const bf16x8*)((const char*)base + row * 128 + (xb ^ ((row & 7) << 4)));
}
__device__ __forceinline__ void st_swz16(__bf16* base, int row, int colbyte, __bf16 v) {
  *(__bf16*)((char*)base + row * 128 + (colbyte ^ ((row & 7) << 4))) = v;
}
__device__ __forceinline__ bf16x8 ld_swz256(const __bf16* base, int row, int xb) {
  return *(const bf16x8*)((const char*)base + row * 256 + (xb ^ ((row & 7) << 4)));
}

__device__ __forceinline__ void attn_tile(
    const __bf16* __restrict__ ks, const __bf16* __restrict__ vs,
    const bool (&okm)[4], __bf16* __restrict__ pw,
    const bf16x8 (&qa)[2], f32x4 (&acc)[4], f32x4& accl,
    const bf16x8 ones, int q0w, int kt, int fc, int kg)
{
  // ---- QK^T (Q pre-scaled by 0.125*log2e) ----
  f32x4 s[4];
  #pragma unroll
  for (int n = 0; n < 4; n++) s[n] = (f32x4)0.f;
  __builtin_amdgcn_s_setprio(1);
  #pragma unroll
  for (int kd = 0; kd < 2; kd++)
    #pragma unroll
    for (int n = 0; n < 4; n++) {
      bf16x8 kf = ld_swz(ks, n * 16 + fc, kd * 64 + kg * 16);
      s[n] = __builtin_amdgcn_mfma_f32_16x16x32_bf16(qa[kd], kf, s[n], 0, 0, 0);
    }
  __builtin_amdgcn_s_setprio(0);

  const int g4 = kg * 4;
  const bool fullt = (kt * 64 + 63 <= q0w);   // wave-uniform: no causal edge
  if (fullt) {
    #pragma unroll
    for (int r = 0; r < 4; r++)
      #pragma unroll
      for (int n = 0; n < 4; n++) {
        float p = okm[n] ? __builtin_amdgcn_exp2f(s[n][r]) : 0.f;
        st_swz16(pw, g4 + r, (n * 16 + fc) * 2, (__bf16)p);
      }
  } else {
    #pragma unroll
    for (int r = 0; r < 4; r++) {
      const int qg = q0w + g4 + r;
      #pragma unroll
      for (int n = 0; n < 4; n++) {
        bool ok = okm[n] && (kt * 64 + n * 16 + fc <= qg);
        float p = ok ? __builtin_amdgcn_exp2f(s[n][r]) : 0.f;
        st_swz16(pw, g4 + r, (n * 16 + fc) * 2, (__bf16)p);
      }
    }
  }

  // ---- PV (+ row-sum l via ones-MFMA) ----
  __builtin_amdgcn_s_setprio(1);
  #pragma unroll
  for (int kc = 0; kc < 2; kc++) {
    bf16x8 pf = ld_swz(pw, fc, kc * 64 + kg * 16);
    accl = __builtin_amdgcn_mfma_f32_16x16x32_bf16(pf, ones, accl, 0, 0, 0);
    #pragma unroll
    for (int n = 0; n < 4; n++) {
      bf16x8 vf = ld_swz(vs, n * 16 + fc, kc * 64 + kg * 16);
      acc[n] = __builtin_amdgcn_mfma_f32_16x16x32_bf16(pf, vf, acc[n], 0, 0, 0);
    }
  }
  __builtin_amdgcn_s_setprio(0);
}

// grid (32, 40): y<32 flash, y>=32 state. LDS = 32 KB exactly ->
// 5 blocks/CU. K double-buffered; V single-buffered, staged after the
// post-compute barrier. qt permutation balances per-CU load.
__global__ __launch_bounds__(256) void flash_state(
    const __bf16* __restrict__ Q, const __bf16* __restrict__ K,
    const __bf16* __restrict__ Vt, const float* __restrict__ mask,
    __bf16* __restrict__ O, const __bf16* __restrict__ Kt,
    float* __restrict__ part)
{
  __shared__ __bf16 SMEM[16384];   // 32 KB: K dbuf 16K | V 8K | Ps 8K

  const int t = threadIdx.x;
  const int w = t >> 6;
  const int lane = t & 63;
  const int fc = lane & 15;
  const int kg = lane >> 4;

  if (blockIdx.y >= 32) {
    // -------- state = K^T V (per head, 256-token slab, 2 chunks) --------
    const int bh = blockIdx.x, sc = blockIdx.y - 32;
    const int b = bh >> 4, h = bh & 15;
    __bf16* Kl = &SMEM[0];
    __bf16* Vl = &SMEM[8192];
    const int rloc = lane >> 4;
    const int cb = (lane & 15) * 16;

    f32x4 acc[4];
    #pragma unroll
    for (int n = 0; n < 4; n++) acc[n] = (f32x4)0.f;

    for (int ch = 0; ch < 2; ch++) {
      const size_t colbase = (size_t)b * S_ + sc * 256 + ch * 128;
      __syncthreads();
      #pragma unroll
      for (int c = 0; c < 4; c++) {
        int row = w * 16 + c * 4 + rloc;
        int scol = (cb ^ ((row & 7) << 4)) >> 1;
        gl16(&Kl[(w * 16 + c * 4) * 128], Kt + (size_t)(h * HD_ + row) * MTOK + colbase + scol);
        gl16(&Vl[(w * 16 + c * 4) * 128], Vt + (size_t)(h * HD_ + row) * MTOK + colbase + scol);
      }
      __syncthreads();

      #pragma unroll
      for (int ks = 0; ks < 4; ks++) {
        bf16x8 af = ld_swz256(Kl, w * 16 + fc, ks * 64 + kg * 16);
        #pragma unroll
        for (int n = 0; n < 4; n++) {
          bf16x8 bfr = ld_swz256(Vl, n * 16 + fc, ks * 64 + kg * 16);
          acc[n] = __builtin_amdgcn_mfma_f32_16x16x32_bf16(af, bfr, acc[n], 0, 0, 0);
        }
      }
    }

    float* dst = part + ((size_t)((bh << 3) + sc) << 12);
    #pragma unroll
    for (int n = 0; n < 4; n++)
      #pragma unroll
      for (int r = 0; r < 4; r++)
        dst[(w * 16 + kg * 4 + r) * 64 + n * 16 + fc] = acc[n][r];
    return;
  }

  // ------------------------- flash attention -------------------------
  const int bh = blockIdx.x;
  const int ya = (int)blockIdx.y & 7;
  const int yg = (int)blockIdx.y >> 3;
  const int qt = (yg == 0) ? 31 - ya : (yg == 1) ? 16 + ya
               : (yg == 2) ? 15 - ya : ya;   // per-CU quadruple sums to 62
  const int b = bh >> 4, h = bh & 15;
  const int g4 = kg * 4;

  const int q0w = qt * 64 + w * 16;
  const size_t tokbase = (size_t)b * S_;

  const int rr = lane >> 3;
  const int cswz = ((lane & 7) ^ rr) * 8;
  const int ktmax = qt;

  __bf16* Vsb = &SMEM[8192];
  __bf16* pw = &SMEM[12288 + w * 1024];

  bf16x8 qa[2];
  {
    const __bf16* qp = Q + (tokbase + q0w + fc) * LDQKV + h * HD_;
    qa[0] = *(const bf16x8*)(qp + kg * 8);
    qa[1] = *(const bf16x8*)(qp + 32 + kg * 8);
  }

  const __bf16* kp0 = K + (tokbase + (size_t)(w * 16 + rr)) * LDQKV + h * HD_ + cswz;
  const __bf16* kp1 = kp0 + (size_t)8 * LDQKV;
  const __bf16* vp0 = Vt + (size_t)(h * HD_ + w * 16 + rr) * MTOK + tokbase + cswz;
  const __bf16* vp1 = vp0 + (size_t)8 * MTOK;

  gl16(&SMEM[(w * 16) * 64],     kp0);
  gl16(&SMEM[(w * 16 + 8) * 64], kp1);
  kp0 += (size_t)64 * LDQKV; kp1 += (size_t)64 * LDQKV;
  gl16(&Vsb[(w * 16) * 64],     vp0);
  gl16(&Vsb[(w * 16 + 8) * 64], vp1);
  vp0 += 64; vp1 += 64;

  const float* mp = mask + tokbase + fc;
  float mnxt[4];
  #pragma unroll
  for (int n = 0; n < 4; n++) mnxt[n] = mp[n * 16];

  bf16x8 ones;
  #pragma unroll
  for (int j = 0; j < 8; j++) ones[j] = (__bf16)1.f;

  f32x4 acc[4], accl;
  #pragma unroll
  for (int n = 0; n < 4; n++) acc[n] = (f32x4)0.f;
  accl = (f32x4)0.f;

  for (int kt = 0; kt <= ktmax; ++kt) {
    float mcur[4];
    #pragma unroll
    for (int n = 0; n < 4; n++) mcur[n] = mnxt[n];

    if (kt < ktmax) {
      #pragma unroll
      for (int n = 0; n < 4; n++) mnxt[n] = mp[(kt + 1) * 64 + n * 16];
      __bf16* kb = &SMEM[((kt + 1) & 1) * 4096];
      gl16(&kb[(w * 16) * 64],     kp0);
      gl16(&kb[(w * 16 + 8) * 64], kp1);
      kp0 += (size_t)64 * LDQKV; kp1 += (size_t)64 * LDQKV;
      asm volatile("s_waitcnt vmcnt(6)" ::: "memory");
    } else {
      asm volatile("s_waitcnt vmcnt(0)" ::: "memory");
    }
    __builtin_amdgcn_sched_barrier(0);
    __builtin_amdgcn_s_barrier();

    bool okm[4];
    #pragma unroll
    for (int n = 0; n < 4; n++) okm[n] = (mcur[n] != 0.f);

    attn_tile(&SMEM[(kt & 1) * 4096], Vsb, okm, pw, qa, acc, accl, ones, q0w, kt, fc, kg);

    __builtin_amdgcn_s_barrier();

    if (kt < ktmax) {
      gl16(&Vsb[(w * 16) * 64],     vp0);
      gl16(&Vsb[(w * 16 + 8) * 64], vp1);
      vp0 += 64; vp1 += 64;
    }
  }

  #pragma unroll
  for (int r = 0; r < 4; r++) {
    float inv = accl[r] > 0.f ? 1.f / accl[r] : 0.f;
    __bf16* op = O + (tokbase + q0w + g4 + r) * HID_ + h * HD_;
    #pragma unroll
    for (int n = 0; n < 4; n++)
      op[n * 16 + fc] = (__bf16)(acc[n][r] * inv);
  }
}

// -------------------------------------------------------------------
extern "C" void kernel_launch(void* const* d_in, const int* in_sizes, int n_in,
                              void* d_out, int out_size, void* d_ws, size_t ws_size,
                              hipStream_t stream)
{
  const float* hs   = (const float*)d_in[0];
  const float* mask = (const float*)d_in[1];
  const float* Wq   = (const float*)d_in[2];
  const float* bq   = (const float*)d_in[3];
  const float* Wk   = (const float*)d_in[4];
  const float* bk   = (const float*)d_in[5];
  const float* Wv   = (const float*)d_in[6];
  const float* bv   = (const float*)d_in[7];
  const float* Wo   = (const float*)d_in[8];
  const float* bo   = (const float*)d_in[9];
  float* out = (float*)d_out;

  char* ws = (char*)d_ws;
  __bf16* Wqkvb = (__bf16*)(ws);                 // 6 MB; dead after gemm_qkv -> part
  __bf16* Wob   = (__bf16*)(ws + (6u  << 20));   // 2 MB; live until gemm_o
  __bf16* Xb    = (__bf16*)(ws + (8u  << 20));   // 8 MB; dead after qkv -> Vt
  __bf16* QKV   = (__bf16*)(ws + (16u << 20));   // 24 MB [4096][3072]
  __bf16* Ob    = (__bf16*)(ws + (40u << 20));   // 8 MB flash output
  __bf16* Ktg   = (__bf16*)(ws + (48u << 20));   // 8 MB [HID][MTOK]

  cast_all<<<2048, 256, 0, stream>>>(hs, Wq, Wk, Wv, Wo, Xb, Wqkvb, Wob);

  gemm_qkv<<<dim3(LDQKV / 128, MTOK / 128), 256, 0, stream>>>(
      Xb, Wqkvb, bq, bk, bv, mask, QKV);

  // Xb dead -> V^T
  __bf16* Vtg = Xb;
  transpose_kv<<<dim3(MTOK / 64, HID_ / 64, 2), 256, 0, stream>>>(
      QKV + 1024, QKV + 2048, Ktg, Vtg);

  // Wqkvb dead -> state partials (32*8*4096 f32 = 4 MB)
  float* part = (float*)Wqkvb;

  flash_state<<<dim3(B_ * NH_, 40), 256, 0, stream>>>(
      QKV, QKV + 1024, Vtg, mask, Ob, Ktg, part);

  gemm_o<<<dim3(HID_ / 128, 34), 256, 0, stream>>>(Ob, Wob, bo, part, out);
}

// Round 18
// 119.095 us; speedup vs baseline: 1.0297x; 1.0026x over previous
//
#include <hip/hip_runtime.h>
#include <hip/hip_bf16.h>

#define B_ 2
#define S_ 2048
#define HID_ 1024
#define NH_ 16
#define HD_ 64
#define MTOK (B_*S_)
#define LDQK 2048
#define SCALE_LOG2E 0.18033688011112043f  /* 0.125 * log2(e), folded into Q */

typedef __attribute__((ext_vector_type(8))) __bf16 bf16x8;
typedef __attribute__((ext_vector_type(4))) __bf16 bf16x4;
typedef __attribute__((ext_vector_type(4))) float f32x4;

__device__ __forceinline__ void gl16(__bf16* lds, const __bf16* g) {
  __builtin_amdgcn_global_load_lds(
      (const __attribute__((address_space(1))) void*)g,
      (__attribute__((address_space(3))) void*)lds, 16, 0, 0);
}

// GEMM tile slot-swizzle: row-dependent 16B-slot XOR inside a 64B row.
__device__ __forceinline__ int gswz(int row) { return ((row ^ (row >> 2)) & 3) << 4; }

// ---------------- fused f32 -> bf16 casts (one launch) -------------
// 2048 blocks, grid-stride 4 float4 per thread (G11).
__global__ __launch_bounds__(256) void cast_all(
    const float* __restrict__ X,
    const float* __restrict__ Wq, const float* __restrict__ Wk,
    const float* __restrict__ Wv, const float* __restrict__ Wo,
    __bf16* __restrict__ Xb, __bf16* __restrict__ Wqkvb, __bf16* __restrict__ Wob)
{
  const int base = blockIdx.x * 256 + threadIdx.x;   // 0..524287
  #pragma unroll
  for (int k = 0; k < 4; k++) {
    int i = base + k * 524288;                       // covers 2M float4 exactly
    const float* src; __bf16* dst; int j;
    if (i < (1 << 20))              { src = X;  dst = Xb;                 j = i; }
    else if (i < (1<<20)+(1<<18))   { src = Wq; dst = Wqkvb;              j = i - (1<<20); }
    else if (i < (1<<20)+(2<<18))   { src = Wk; dst = Wqkvb + (1<<20);    j = i - (1<<20) - (1<<18); }
    else if (i < (1<<20)+(3<<18))   { src = Wv; dst = Wqkvb + (2<<20);    j = i - (1<<20) - (2<<18); }
    else                            { src = Wo; dst = Wob;                j = i - (1<<20) - (3<<18); }
    float4 v = reinterpret_cast<const float4*>(src)[j];
    bf16x4 o;
    o[0] = (__bf16)v.x; o[1] = (__bf16)v.y; o[2] = (__bf16)v.z; o[3] = (__bf16)v.w;
    reinterpret_cast<bf16x4*>(dst)[j] = o;
  }
}

// ---------------- QKV projection, fused transposed outputs ---------
// C(QK) = X @ Wqk^T row-major (Q pre-scaled); K also -> Kt [feat][tok];
// V -> Vt ONLY (row-major V is never read downstream).
// 3-buffer LDS, 2-step-ahead prefetch, ONE barrier per K-step.
__global__ __launch_bounds__(256) void gemm_qkv(
    const __bf16* __restrict__ A, const __bf16* __restrict__ W,
    const float* __restrict__ bq, const float* __restrict__ bk,
    const float* __restrict__ bv, const float* __restrict__ mask,
    __bf16* __restrict__ C, __bf16* __restrict__ Kt, __bf16* __restrict__ Vt)
{
  __shared__ __bf16 SM[24576];              // 48 KB: 3x(A 8KB) + 3x(B 8KB)
  const int t = threadIdx.x;
  const int m0 = blockIdx.y * 128;
  const int n0 = blockIdx.x * 128;
  const int lane = t & 63;
  const int w = t >> 6;
  const int wr = (w >> 1) * 64;
  const int wc = (w & 1) * 64;
  const int fr = lane & 15;
  const int kg = lane >> 4;

  f32x4 acc[4][4];
  #pragma unroll
  for (int i = 0; i < 4; i++)
    #pragma unroll
    for (int j = 0; j < 4; j++) acc[i][j] = (f32x4)0.f;

  const int srow = w * 16 + (lane >> 2);
  const int scolb = ((lane & 3) * 16) ^ gswz(srow);
  const __bf16* ap0 = A + (size_t)(m0 + srow) * HID_ + (scolb >> 1);
  const __bf16* ap1 = A + (size_t)(m0 + 64 + srow) * HID_ + (scolb >> 1);
  const __bf16* wp0 = W + (size_t)(n0 + srow) * HID_ + (scolb >> 1);
  const __bf16* wp1 = W + (size_t)(n0 + 64 + srow) * HID_ + (scolb >> 1);

  #define STAGE3(buf, koff) { \
    __bf16* ab = SM + (buf) * 4096; \
    __bf16* bb = SM + 12288 + (buf) * 4096; \
    gl16(ab + w * 512, ap0 + (koff)); \
    gl16(ab + 2048 + w * 512, ap1 + (koff)); \
    gl16(bb + w * 512, wp0 + (koff)); \
    gl16(bb + 2048 + w * 512, wp1 + (koff)); }

  STAGE3(0, 0);
  STAGE3(1, 32);
  int bc = 0, bp2 = 2;
  for (int step = 0; step < 32; ++step) {
    if (step + 1 < 32) { asm volatile("s_waitcnt vmcnt(4)" ::: "memory"); }
    else               { asm volatile("s_waitcnt vmcnt(0)" ::: "memory"); }
    __builtin_amdgcn_sched_barrier(0);
    __builtin_amdgcn_s_barrier();
    if (step + 2 < 32) STAGE3(bp2, (step + 2) * 32);

    const __bf16* ab = SM + bc * 4096;
    const __bf16* bb = SM + 12288 + bc * 4096;
    bf16x8 af[4], bf[4];
    #pragma unroll
    for (int m = 0; m < 4; m++) {
      int row = wr + m*16 + fr;
      af[m] = *(const bf16x8*)((const char*)ab + row * 64 + ((kg * 16) ^ gswz(row)));
    }
    #pragma unroll
    for (int n = 0; n < 4; n++) {
      int row = wc + n*16 + fr;
      bf[n] = *(const bf16x8*)((const char*)bb + row * 64 + ((kg * 16) ^ gswz(row)));
    }
    #pragma unroll
    for (int m = 0; m < 4; m++)
      #pragma unroll
      for (int n = 0; n < 4; n++)
        acc[m][n] = __builtin_amdgcn_mfma_f32_16x16x32_bf16(af[m], bf[n], acc[m][n], 0, 0, 0);

    bc = (bc == 2) ? 0 : bc + 1;
    bp2 = (bp2 == 2) ? 0 : bp2 + 1;
  }

  const int region = n0 >> 10;               // 0=Q 1=K 2=V (block-uniform)
  const int nloc = n0 & 1023;

  if (region == 2) {
    // ---- V: transposed-only store, Vt[feat][tok], 8B per (m,n) ----
    #pragma unroll
    for (int m = 0; m < 4; m++) {
      const int tok0 = m0 + wr + m*16 + kg*4;
      float rs0 = mask[tok0], rs1 = mask[tok0+1], rs2 = mask[tok0+2], rs3 = mask[tok0+3];
      #pragma unroll
      for (int n = 0; n < 4; n++) {
        int c = nloc + wc + n*16 + fr;
        float bb_ = bv[c];
        bf16x4 o;
        o[0] = (__bf16)((acc[m][n][0] + bb_) * rs0);
        o[1] = (__bf16)((acc[m][n][1] + bb_) * rs1);
        o[2] = (__bf16)((acc[m][n][2] + bb_) * rs2);
        o[3] = (__bf16)((acc[m][n][3] + bb_) * rs3);
        *(bf16x4*)(Vt + (size_t)c * MTOK + tok0) = o;
      }
    }
    return;
  }

  const float* bias = region == 0 ? bq : bk;
  #pragma unroll
  for (int m = 0; m < 4; m++) {
    #pragma unroll
    for (int r = 0; r < 4; r++) {
      int row = m0 + wr + m*16 + kg*4 + r;
      float rs = region ? mask[row] : SCALE_LOG2E;
      #pragma unroll
      for (int n = 0; n < 4; n++) {
        int c = wc + n*16 + fr;
        C[(size_t)row * LDQK + n0 + c] = (__bf16)((acc[m][n][r] + bias[nloc + c]) * rs);
      }
    }
  }

  if (region == 1) {
    // ---- K also transposed -> Kt[feat][tok] ----
    #pragma unroll
    for (int m = 0; m < 4; m++) {
      const int tok0 = m0 + wr + m*16 + kg*4;
      float rs0 = mask[tok0], rs1 = mask[tok0+1], rs2 = mask[tok0+2], rs3 = mask[tok0+3];
      #pragma unroll
      for (int n = 0; n < 4; n++) {
        int c = nloc + wc + n*16 + fr;
        float bb_ = bk[c];
        bf16x4 o;
        o[0] = (__bf16)((acc[m][n][0] + bb_) * rs0);
        o[1] = (__bf16)((acc[m][n][1] + bb_) * rs1);
        o[2] = (__bf16)((acc[m][n][2] + bb_) * rs2);
        o[3] = (__bf16)((acc[m][n][3] + bb_) * rs3);
        *(bf16x4*)(Kt + (size_t)c * MTOK + tok0) = o;
      }
    }
  }
}

// ---------------- O projection + state reduction tail --------------
// grid (8, 34): y<32 GEMM 128x128; y>=32 reduce 8 state partials.
__global__ __launch_bounds__(256) void gemm_o(
    const __bf16* __restrict__ A, const __bf16* __restrict__ W,
    const float* __restrict__ bias, const float* __restrict__ part,
    float* __restrict__ C)
{
  if (blockIdx.y >= 32) {
    const int bl = blockIdx.x + (blockIdx.y - 32) * 8;   // 0..15
    const int tid = bl * 256 + threadIdx.x;              // 0..4095
    float* outState = C + (size_t)MTOK * HID_;
    #pragma unroll 4
    for (int e = 0; e < 32; e++) {
      int i = e * 4096 + tid;
      int bh = i >> 12, de = i & 4095;
      float s = 0.f;
      #pragma unroll
      for (int sc = 0; sc < 8; sc++) s += part[(size_t)((bh << 3) + sc) * 4096 + de];
      outState[i] = s;
    }
    return;
  }

  __shared__ __bf16 SM[24576];
  const int t = threadIdx.x;
  const int m0 = blockIdx.y * 128;
  const int n0 = blockIdx.x * 128;
  const int lane = t & 63;
  const int w = t >> 6;
  const int wr = (w >> 1) * 64;
  const int wc = (w & 1) * 64;
  const int fr = lane & 15;
  const int kg = lane >> 4;

  f32x4 acc[4][4];
  #pragma unroll
  for (int i = 0; i < 4; i++)
    #pragma unroll
    for (int j = 0; j < 4; j++) acc[i][j] = (f32x4)0.f;

  const int srow = w * 16 + (lane >> 2);
  const int scolb = ((lane & 3) * 16) ^ gswz(srow);
  const __bf16* ap0 = A + (size_t)(m0 + srow) * HID_ + (scolb >> 1);
  const __bf16* ap1 = A + (size_t)(m0 + 64 + srow) * HID_ + (scolb >> 1);
  const __bf16* wp0 = W + (size_t)(n0 + srow) * HID_ + (scolb >> 1);
  const __bf16* wp1 = W + (size_t)(n0 + 64 + srow) * HID_ + (scolb >> 1);

  STAGE3(0, 0);
  STAGE3(1, 32);
  int bc = 0, bp2 = 2;
  for (int step = 0; step < 32; ++step) {
    if (step + 1 < 32) { asm volatile("s_waitcnt vmcnt(4)" ::: "memory"); }
    else               { asm volatile("s_waitcnt vmcnt(0)" ::: "memory"); }
    __builtin_amdgcn_sched_barrier(0);
    __builtin_amdgcn_s_barrier();
    if (step + 2 < 32) STAGE3(bp2, (step + 2) * 32);

    const __bf16* ab = SM + bc * 4096;
    const __bf16* bb = SM + 12288 + bc * 4096;
    bf16x8 af[4], bf[4];
    #pragma unroll
    for (int m = 0; m < 4; m++) {
      int row = wr + m*16 + fr;
      af[m] = *(const bf16x8*)((const char*)ab + row * 64 + ((kg * 16) ^ gswz(row)));
    }
    #pragma unroll
    for (int n = 0; n < 4; n++) {
      int row = wc + n*16 + fr;
      bf[n] = *(const bf16x8*)((const char*)bb + row * 64 + ((kg * 16) ^ gswz(row)));
    }
    #pragma unroll
    for (int m = 0; m < 4; m++)
      #pragma unroll
      for (int n = 0; n < 4; n++)
        acc[m][n] = __builtin_amdgcn_mfma_f32_16x16x32_bf16(af[m], bf[n], acc[m][n], 0, 0, 0);

    bc = (bc == 2) ? 0 : bc + 1;
    bp2 = (bp2 == 2) ? 0 : bp2 + 1;
  }

  #pragma unroll
  for (int m = 0; m < 4; m++) {
    #pragma unroll
    for (int r = 0; r < 4; r++) {
      int row = m0 + wr + m*16 + kg*4 + r;
      #pragma unroll
      for (int n = 0; n < 4; n++) {
        int col = n0 + wc + n*16 + fr;
        C[(size_t)row * HID_ + col] = acc[m][n][r] + bias[col];
      }
    }
  }
}

// ---------------- flash attention + fused state tail ---------------
__device__ __forceinline__ bf16x8 ld_swz(const __bf16* base, int row, int xb) {
  return *(const bf16x8*)((const char*)base + row * 128 + (xb ^ ((row & 7) << 4)));
}
__device__ __forceinline__ void st_swz16(__bf16* base, int row, int colbyte, __bf16 v) {
  *(__bf16*)((char*)base + row * 128 + (colbyte ^ ((row & 7) << 4))) = v;
}
__device__ __forceinline__ bf16x8 ld_swz256(const __bf16* base, int row, int xb) {
  return *(const bf16x8*)((const char*)base + row * 256 + (xb ^ ((row & 7) << 4)));
}

__device__ __forceinline__ void attn_tile(
    const __bf16* __restrict__ ks, const __bf16* __restrict__ vs,
    const bool (&okm)[4], __bf16* __restrict__ pw,
    const bf16x8 (&qa)[2], f32x4 (&acc)[4], f32x4& accl,
    const bf16x8 ones, int q0w, int kt, int fc, int kg)
{
  // ---- QK^T (Q pre-scaled by 0.125*log2e) ----
  f32x4 s[4];
  #pragma unroll
  for (int n = 0; n < 4; n++) s[n] = (f32x4)0.f;
  __builtin_amdgcn_s_setprio(1);
  #pragma unroll
  for (int kd = 0; kd < 2; kd++)
    #pragma unroll
    for (int n = 0; n < 4; n++) {
      bf16x8 kf = ld_swz(ks, n * 16 + fc, kd * 64 + kg * 16);
      s[n] = __builtin_amdgcn_mfma_f32_16x16x32_bf16(qa[kd], kf, s[n], 0, 0, 0);
    }
  __builtin_amdgcn_s_setprio(0);

  const int g4 = kg * 4;
  const bool fullt = (kt * 64 + 63 <= q0w);   // wave-uniform: no causal edge
  if (fullt) {
    #pragma unroll
    for (int r = 0; r < 4; r++)
      #pragma unroll
      for (int n = 0; n < 4; n++) {
        float p = okm[n] ? __builtin_amdgcn_exp2f(s[n][r]) : 0.f;
        st_swz16(pw, g4 + r, (n * 16 + fc) * 2, (__bf16)p);
      }
  } else {
    #pragma unroll
    for (int r = 0; r < 4; r++) {
      const int qg = q0w + g4 + r;
      #pragma unroll
      for (int n = 0; n < 4; n++) {
        bool ok = okm[n] && (kt * 64 + n * 16 + fc <= qg);
        float p = ok ? __builtin_amdgcn_exp2f(s[n][r]) : 0.f;
        st_swz16(pw, g4 + r, (n * 16 + fc) * 2, (__bf16)p);
      }
    }
  }

  // ---- PV (+ row-sum l via ones-MFMA) ----
  __builtin_amdgcn_s_setprio(1);
  #pragma unroll
  for (int kc = 0; kc < 2; kc++) {
    bf16x8 pf = ld_swz(pw, fc, kc * 64 + kg * 16);
    accl = __builtin_amdgcn_mfma_f32_16x16x32_bf16(pf, ones, accl, 0, 0, 0);
    #pragma unroll
    for (int n = 0; n < 4; n++) {
      bf16x8 vf = ld_swz(vs, n * 16 + fc, kc * 64 + kg * 16);
      acc[n] = __builtin_amdgcn_mfma_f32_16x16x32_bf16(pf, vf, acc[n], 0, 0, 0);
    }
  }
  __builtin_amdgcn_s_setprio(0);
}

// grid (32, 40): y<32 flash, y>=32 state. LDS = 32 KB exactly ->
// 5 blocks/CU. K double-buffered; V single-buffered, staged after the
// post-compute barrier. qt permutation balances per-CU load.
__global__ __launch_bounds__(256) void flash_state(
    const __bf16* __restrict__ Q, const __bf16* __restrict__ K,
    const __bf16* __restrict__ Vt, const float* __restrict__ mask,
    __bf16* __restrict__ O, const __bf16* __restrict__ Kt,
    float* __restrict__ part)
{
  __shared__ __bf16 SMEM[16384];   // 32 KB: K dbuf 16K | V 8K | Ps 8K

  const int t = threadIdx.x;
  const int w = t >> 6;
  const int lane = t & 63;
  const int fc = lane & 15;
  const int kg = lane >> 4;

  if (blockIdx.y >= 32) {
    // -------- state = K^T V (per head, 256-token slab, 2 chunks) --------
    const int bh = blockIdx.x, sc = blockIdx.y - 32;
    const int b = bh >> 4, h = bh & 15;
    __bf16* Kl = &SMEM[0];
    __bf16* Vl = &SMEM[8192];
    const int rloc = lane >> 4;
    const int cb = (lane & 15) * 16;

    f32x4 acc[4];
    #pragma unroll
    for (int n = 0; n < 4; n++) acc[n] = (f32x4)0.f;

    for (int ch = 0; ch < 2; ch++) {
      const size_t colbase = (size_t)b * S_ + sc * 256 + ch * 128;
      __syncthreads();
      #pragma unroll
      for (int c = 0; c < 4; c++) {
        int row = w * 16 + c * 4 + rloc;
        int scol = (cb ^ ((row & 7) << 4)) >> 1;
        gl16(&Kl[(w * 16 + c * 4) * 128], Kt + (size_t)(h * HD_ + row) * MTOK + colbase + scol);
        gl16(&Vl[(w * 16 + c * 4) * 128], Vt + (size_t)(h * HD_ + row) * MTOK + colbase + scol);
      }
      __syncthreads();

      #pragma unroll
      for (int ks = 0; ks < 4; ks++) {
        bf16x8 af = ld_swz256(Kl, w * 16 + fc, ks * 64 + kg * 16);
        #pragma unroll
        for (int n = 0; n < 4; n++) {
          bf16x8 bfr = ld_swz256(Vl, n * 16 + fc, ks * 64 + kg * 16);
          acc[n] = __builtin_amdgcn_mfma_f32_16x16x32_bf16(af, bfr, acc[n], 0, 0, 0);
        }
      }
    }

    float* dst = part + ((size_t)((bh << 3) + sc) << 12);
    #pragma unroll
    for (int n = 0; n < 4; n++)
      #pragma unroll
      for (int r = 0; r < 4; r++)
        dst[(w * 16 + kg * 4 + r) * 64 + n * 16 + fc] = acc[n][r];
    return;
  }

  // ------------------------- flash attention -------------------------
  const int bh = blockIdx.x;
  const int ya = (int)blockIdx.y & 7;
  const int yg = (int)blockIdx.y >> 3;
  const int qt = (yg == 0) ? 31 - ya : (yg == 1) ? 16 + ya
               : (yg == 2) ? 15 - ya : ya;   // per-CU quadruple sums to 62
  const int b = bh >> 4, h = bh & 15;
  const int g4 = kg * 4;

  const int q0w = qt * 64 + w * 16;
  const size_t tokbase = (size_t)b * S_;

  const int rr = lane >> 3;
  const int cswz = ((lane & 7) ^ rr) * 8;
  const int ktmax = qt;

  __bf16* Vsb = &SMEM[8192];
  __bf16* pw = &SMEM[12288 + w * 1024];

  bf16x8 qa[2];
  {
    const __bf16* qp = Q + (tokbase + q0w + fc) * LDQK + h * HD_;
    qa[0] = *(const bf16x8*)(qp + kg * 8);
    qa[1] = *(const bf16x8*)(qp + 32 + kg * 8);
  }

  const __bf16* kp0 = K + (tokbase + (size_t)(w * 16 + rr)) * LDQK + h * HD_ + cswz;
  const __bf16* kp1 = kp0 + (size_t)8 * LDQK;
  const __bf16* vp0 = Vt + (size_t)(h * HD_ + w * 16 + rr) * MTOK + tokbase + cswz;
  const __bf16* vp1 = vp0 + (size_t)8 * MTOK;

  gl16(&SMEM[(w * 16) * 64],     kp0);
  gl16(&SMEM[(w * 16 + 8) * 64], kp1);
  kp0 += (size_t)64 * LDQK; kp1 += (size_t)64 * LDQK;
  gl16(&Vsb[(w * 16) * 64],     vp0);
  gl16(&Vsb[(w * 16 + 8) * 64], vp1);
  vp0 += 64; vp1 += 64;

  const float* mp = mask + tokbase + fc;
  float mnxt[4];
  #pragma unroll
  for (int n = 0; n < 4; n++) mnxt[n] = mp[n * 16];

  bf16x8 ones;
  #pragma unroll
  for (int j = 0; j < 8; j++) ones[j] = (__bf16)1.f;

  f32x4 acc[4], accl;
  #pragma unroll
  for (int n = 0; n < 4; n++) acc[n] = (f32x4)0.f;
  accl = (f32x4)0.f;

  for (int kt = 0; kt <= ktmax; ++kt) {
    float mcur[4];
    #pragma unroll
    for (int n = 0; n < 4; n++) mcur[n] = mnxt[n];

    if (kt < ktmax) {
      #pragma unroll
      for (int n = 0; n < 4; n++) mnxt[n] = mp[(kt + 1) * 64 + n * 16];
      __bf16* kb = &SMEM[((kt + 1) & 1) * 4096];
      gl16(&kb[(w * 16) * 64],     kp0);
      gl16(&kb[(w * 16 + 8) * 64], kp1);
      kp0 += (size_t)64 * LDQK; kp1 += (size_t)64 * LDQK;
      asm volatile("s_waitcnt vmcnt(6)" ::: "memory");
    } else {
      asm volatile("s_waitcnt vmcnt(0)" ::: "memory");
    }
    __builtin_amdgcn_sched_barrier(0);
    __builtin_amdgcn_s_barrier();

    bool okm[4];
    #pragma unroll
    for (int n = 0; n < 4; n++) okm[n] = (mcur[n] != 0.f);

    attn_tile(&SMEM[(kt & 1) * 4096], Vsb, okm, pw, qa, acc, accl, ones, q0w, kt, fc, kg);

    __builtin_amdgcn_s_barrier();

    if (kt < ktmax) {
      gl16(&Vsb[(w * 16) * 64],     vp0);
      gl16(&Vsb[(w * 16 + 8) * 64], vp1);
      vp0 += 64; vp1 += 64;
    }
  }

  #pragma unroll
  for (int r = 0; r < 4; r++) {
    float inv = accl[r] > 0.f ? 1.f / accl[r] : 0.f;
    __bf16* op = O + (tokbase + q0w + g4 + r) * HID_ + h * HD_;
    #pragma unroll
    for (int n = 0; n < 4; n++)
      op[n * 16 + fc] = (__bf16)(acc[n][r] * inv);
  }
}

// -------------------------------------------------------------------
extern "C" void kernel_launch(void* const* d_in, const int* in_sizes, int n_in,
                              void* d_out, int out_size, void* d_ws, size_t ws_size,
                              hipStream_t stream)
{
  const float* hs   = (const float*)d_in[0];
  const float* mask = (const float*)d_in[1];
  const float* Wq   = (const float*)d_in[2];
  const float* bq   = (const float*)d_in[3];
  const float* Wk   = (const float*)d_in[4];
  const float* bk   = (const float*)d_in[5];
  const float* Wv   = (const float*)d_in[6];
  const float* bv   = (const float*)d_in[7];
  const float* Wo   = (const float*)d_in[8];
  const float* bo   = (const float*)d_in[9];
  float* out = (float*)d_out;

  char* ws = (char*)d_ws;
  __bf16* Wqkvb = (__bf16*)(ws);                 // 6 MB; dead after gemm_qkv -> part
  __bf16* Wob   = (__bf16*)(ws + (6u  << 20));   // 2 MB; live until gemm_o
  __bf16* Xb    = (__bf16*)(ws + (8u  << 20));   // 8 MB; dead after gemm_qkv
  __bf16* QK    = (__bf16*)(ws + (16u << 20));   // 16 MB [4096][2048] (Q|K)
  __bf16* Vtg   = (__bf16*)(ws + (32u << 20));   // 8 MB [HID][MTOK] (fresh)
  __bf16* Ob    = (__bf16*)(ws + (40u << 20));   // 8 MB flash output
  __bf16* Ktg   = (__bf16*)(ws + (48u << 20));   // 8 MB [HID][MTOK]

  cast_all<<<2048, 256, 0, stream>>>(hs, Wq, Wk, Wv, Wo, Xb, Wqkvb, Wob);

  gemm_qkv<<<dim3(3072 / 128, MTOK / 128), 256, 0, stream>>>(
      Xb, Wqkvb, bq, bk, bv, mask, QK, Ktg, Vtg);

  // Wqkvb dead -> state partials (32*8*4096 f32 = 4 MB)
  float* part = (float*)Wqkvb;

  flash_state<<<dim3(B_ * NH_, 40), 256, 0, stream>>>(
      QK, QK + 1024, Vtg, mask, Ob, Ktg, part);

  gemm_o<<<dim3(HID_ / 128, 34), 256, 0, stream>>>(Ob, Wob, bo, part, out);
}